// Round 1
// baseline (182.121 us; speedup 1.0000x reference)
//
#include <hip/hip_runtime.h>

#define T_DIM 8192
#define NTH 1024
#define NWAVE 16
#define KEEP_K 2867   // max(1, round(8192 * 0.35))

__global__ __launch_bounds__(NTH) void srp_kernel(
    const float* __restrict__ g_anchor,
    const float* __restrict__ g_lr,
    const float* __restrict__ g_pw,
    const float* __restrict__ g_bl,
    const float* __restrict__ g_mask,
    const float* __restrict__ g_sbud,
    const float* __restrict__ g_pbud,
    const float* __restrict__ g_psp,
    const float* __restrict__ g_ppa,
    const int*  __restrict__ g_front,
    float* __restrict__ g_out,
    int n_rows)
{
    constexpr float MIN_SPEECH = 1.0f;
    constexpr float MAX_EXPAND = 3.0f;
    constexpr float MIN_BW = 0.1f;
    constexpr float BIAS_W = 0.15f;
    constexpr float INV_TEMP = 1.0f / 0.12f;

    __shared__ float sc[T_DIM];                 // 32 KB: scores
    __shared__ unsigned hist[NWAVE][256];       // 16 KB: per-wave radix histograms
    __shared__ float wred[NWAVE][4];            // block reduction scratch
    __shared__ float s_scal[6];                 // row scalars
    __shared__ unsigned s_tot[256];             // reduced histogram
    __shared__ unsigned sh_prefix;
    __shared__ unsigned sh_k;

    const int b = blockIdx.x;
    const int tid = threadIdx.x;
    const int wave = tid >> 6;
    const int lane = tid & 63;
    const long long row = (long long)b * T_DIM;
    const int f = g_front[b];

    // per-element output ingredients kept in registers (8 elems/thread)
    float A[8], Pp[8], Cc[8], Mm[8], TC[8];
    float a_ps = 0.f, a_pp = 0.f, a_ts = 0.f, a_cs = 0.f;

    // ---------- Pass 1: load everything once, compute sums, stash scores ----------
    #pragma unroll
    for (int j = 0; j < 2; ++j) {
        const int t0 = j * 4096 + (tid << 2);
        const float4 an4 = *reinterpret_cast<const float4*>(g_anchor + row + t0);
        const float4 lr4 = *reinterpret_cast<const float4*>(g_lr + row + t0);
        const float4 pw4 = *reinterpret_cast<const float4*>(g_pw + row + t0);
        const float4 bl4 = *reinterpret_cast<const float4*>(g_bl + row + t0);
        const float4 mk4 = *reinterpret_cast<const float4*>(g_mask + row + t0);
        const float4 ps4 = *reinterpret_cast<const float4*>(g_psp + row + t0);
        const float4 pp4 = *reinterpret_cast<const float4*>(g_ppa + row + t0);
        float4 s4;
        #pragma unroll
        for (int c = 0; c < 4; ++c) {
            const int i = (j << 2) + c;
            const int t = t0 + c;
            const float m   = (&mk4.x)[c];
            const float pre = (t < f) ? 1.0f : 0.0f;
            const float tail = m * (1.0f - pre);
            const float ps = (&ps4.x)[c];
            const float pp = (&pp4.x)[c];
            a_ps += ps * m * pre;
            a_pp += pp * m * pre;
            a_ts += tail;
            const float an = fmaxf((&an4.x)[c], MIN_SPEECH);
            const float cand = fminf(fmaxf(an * __expf((&lr4.x)[c]), MIN_SPEECH),
                                     an * MAX_EXPAND) * m;
            a_cs += cand * tail;
            const float s = (fmaxf((&pw4.x)[c], 0.0f)
                             + BIAS_W * (MIN_BW + fmaxf((&bl4.x)[c], 0.0f))) * m;
            (&s4.x)[c] = s;
            A[i]  = ps * m * m * pre;        // speech prefix term (incl. outer mask)
            Pp[i] = pp * m * m * pre;        // pause prefix term
            Cc[i] = cand * tail * m;         // speech tail coefficient
            Mm[i] = m;
        }
        *reinterpret_cast<float4*>(&sc[t0]) = s4;
    }

    // ---------- block reduce 4 accumulators ----------
    #pragma unroll
    for (int o = 32; o > 0; o >>= 1) {
        a_ps += __shfl_down(a_ps, o, 64);
        a_pp += __shfl_down(a_pp, o, 64);
        a_ts += __shfl_down(a_ts, o, 64);
        a_cs += __shfl_down(a_cs, o, 64);
    }
    if (lane == 0) {
        wred[wave][0] = a_ps; wred[wave][1] = a_pp;
        wred[wave][2] = a_ts; wred[wave][3] = a_cs;
    }
    __syncthreads();
    if (tid == 0) {
        float ps = 0.f, pp = 0.f, ts = 0.f, cs = 0.f;
        for (int w = 0; w < NWAVE; ++w) {
            ps += wred[w][0]; pp += wred[w][1];
            ts += wred[w][2]; cs += wred[w][3];
        }
        const float sb = fmaxf(g_sbud[b], ps + ts * MIN_SPEECH);
        const float pb = fmaxf(g_pbud[b], pp);
        const float rem_s = sb - ps;
        const float cts = fmaxf(cs, 1e-6f);
        s_scal[0] = (ts > 0.0f && rem_s > 0.0f) ? (rem_s / cts) : 0.0f;  // scale_s
        s_scal[1] = fmaxf(pb - pp, 0.0f);                                // rem_p
        s_scal[2] = ts;
        s_scal[3] = fmaxf(ts, 1.0f);
        sh_prefix = 0u;
        sh_k = KEEP_K;
    }

    // ---------- exact kth-largest via radix-8 select on float bits ----------
    for (int pass = 0; pass < 4; ++pass) {
        const int shift = 24 - pass * 8;
        for (int d = lane; d < 256; d += 64) hist[wave][d] = 0u;
        __syncthreads();
        const unsigned pfx = sh_prefix;
        const unsigned hm = (pass == 0) ? 0u : (0xFFFFFFFFu << (shift + 8));
        #pragma unroll
        for (int j = 0; j < 2; ++j) {
            const int t0 = j * 4096 + (tid << 2);
            const float4 s4 = *reinterpret_cast<const float4*>(&sc[t0]);
            #pragma unroll
            for (int c = 0; c < 4; ++c) {
                const unsigned bits = __float_as_uint((&s4.x)[c]);
                if ((bits & hm) == pfx)
                    atomicAdd(&hist[wave][(bits >> shift) & 0xFFu], 1u);
            }
        }
        __syncthreads();
        if (tid < 256) {
            unsigned s = 0;
            for (int w = 0; w < NWAVE; ++w) s += hist[w][tid];
            s_tot[tid] = s;
        }
        __syncthreads();
        if (wave == 0) {
            const unsigned k = sh_k;
            const int r0 = lane * 4;
            const unsigned c0 = s_tot[255 - r0];
            const unsigned c1 = s_tot[255 - (r0 + 1)];
            const unsigned c2 = s_tot[255 - (r0 + 2)];
            const unsigned c3 = s_tot[255 - (r0 + 3)];
            const unsigned s1 = c0 + c1, s2 = s1 + c2, s3 = s2 + c3;
            unsigned tot = s3;
            #pragma unroll
            for (int off = 1; off < 64; off <<= 1) {
                const unsigned n = __shfl_up(tot, off, 64);
                if (lane >= off) tot += n;
            }
            const unsigned excl = tot - s3;
            const unsigned Pc[4] = { excl + c0, excl + s1, excl + s2, excl + s3 };
            unsigned prev = excl;
            #pragma unroll
            for (int c = 0; c < 4; ++c) {
                if (Pc[c] >= k && prev < k) {
                    sh_prefix = pfx | ((unsigned)(255 - (r0 + c)) << shift);
                    sh_k = k - prev;
                }
                prev = Pc[c];
            }
        }
        __syncthreads();
    }
    const float thr = __uint_as_float(sh_prefix);

    // ---------- Pass 2: gated denominator ----------
    const float inv_ts6 = 1e-6f / s_scal[3];
    float a_d = 0.0f;
    #pragma unroll
    for (int j = 0; j < 2; ++j) {
        const int t0 = j * 4096 + (tid << 2);
        const float4 s4 = *reinterpret_cast<const float4*>(&sc[t0]);
        #pragma unroll
        for (int c = 0; c < 4; ++c) {
            const int i = (j << 2) + c;
            const int t = t0 + c;
            const float m = Mm[i];
            const float pre = (t < f) ? 1.0f : 0.0f;
            const float tail = m * (1.0f - pre);
            const float s = (&s4.x)[c];
            const float gate = 1.0f / (1.0f + __expf(-(s - thr) * INV_TEMP));
            const float tc = s * gate * m * tail + tail * inv_ts6;  // tail_cand
            a_d += tc * tail;          // denom contribution
            TC[i] = tc * tail * m;     // pause tail coefficient
        }
    }
    #pragma unroll
    for (int o = 32; o > 0; o >>= 1) a_d += __shfl_down(a_d, o, 64);
    if (lane == 0) wred[wave][0] = a_d;
    __syncthreads();
    if (tid == 0) {
        float d = 0.f;
        for (int w = 0; w < NWAVE; ++w) d += wred[w][0];
        const float denom = fmaxf(d, 1e-6f);
        const float ts = s_scal[2];
        const float rem_p = s_scal[1];
        s_scal[4] = (ts > 0.0f && rem_p > 0.0f) ? (rem_p / denom) : 0.0f;  // scale_p
    }
    __syncthreads();

    // ---------- Pass 3: write outputs ----------
    const float scale_s = s_scal[0];
    const float scale_p = s_scal[4];
    const long long out_off = (long long)n_rows * T_DIM;
    #pragma unroll
    for (int j = 0; j < 2; ++j) {
        const int t0 = j * 4096 + (tid << 2);
        float4 vs, vp;
        #pragma unroll
        for (int c = 0; c < 4; ++c) {
            const int i = (j << 2) + c;
            (&vs.x)[c] = A[i]  + Cc[i] * scale_s;
            (&vp.x)[c] = Pp[i] + TC[i] * scale_p;
        }
        *reinterpret_cast<float4*>(g_out + row + t0) = vs;
        *reinterpret_cast<float4*>(g_out + out_off + row + t0) = vp;
    }
}

extern "C" void kernel_launch(void* const* d_in, const int* in_sizes, int n_in,
                              void* d_out, int out_size, void* d_ws, size_t ws_size,
                              hipStream_t stream) {
    const float* anchor = (const float*)d_in[0];
    const float* lr     = (const float*)d_in[1];
    const float* pw     = (const float*)d_in[2];
    const float* bl     = (const float*)d_in[3];
    const float* mask   = (const float*)d_in[4];
    const float* sbud   = (const float*)d_in[5];
    const float* pbud   = (const float*)d_in[6];
    const float* psp    = (const float*)d_in[7];
    const float* ppa    = (const float*)d_in[8];
    const int*   front  = (const int*)d_in[9];
    float* out = (float*)d_out;
    const int B = in_sizes[5];   // speech_budget_win has B elements
    srp_kernel<<<B, NTH, 0, stream>>>(anchor, lr, pw, bl, mask, sbud, pbud,
                                      psp, ppa, front, out, B);
}

// Round 3
// 171.163 us; speedup vs baseline: 1.0640x; 1.0640x over previous
//
#include <hip/hip_runtime.h>

#define T_DIM 8192
#define NTH 1024
#define NWAVE 16
#define KEEP_K 2867                 // max(1, round(8192 * 0.35))
#define KSCALE 32768.0f             // 16-bit fixed-point key scale (scores < 2.0)
#define INV_KSCALE (1.0f / 32768.0f)

typedef float nt4 __attribute__((ext_vector_type(4)));  // native vec for nontemporal store

// Scan 256-bin histogram from the top, find digit where cumulative count
// reaches k. Executed by wave 0 only. Writes digit and residual k to shared.
__device__ __forceinline__ void scan_top256(const unsigned* bins, unsigned k, int lane,
                                            unsigned* sh_digit, unsigned* sh_k) {
    const int r0 = lane * 4;
    const unsigned c0 = bins[255 - r0];
    const unsigned c1 = bins[255 - (r0 + 1)];
    const unsigned c2 = bins[255 - (r0 + 2)];
    const unsigned c3 = bins[255 - (r0 + 3)];
    const unsigned s1 = c0 + c1, s2 = s1 + c2, s3 = s2 + c3;
    unsigned tot = s3;
    #pragma unroll
    for (int off = 1; off < 64; off <<= 1) {
        const unsigned n = __shfl_up(tot, off, 64);
        if (lane >= off) tot += n;
    }
    const unsigned excl = tot - s3;
    const unsigned Pc[4] = { excl + c0, excl + s1, excl + s2, excl + s3 };
    unsigned prev = excl;
    #pragma unroll
    for (int c = 0; c < 4; ++c) {
        if (Pc[c] >= k && prev < k) {
            *sh_digit = (unsigned)(255 - (r0 + c));
            *sh_k = k - prev;
        }
        prev = Pc[c];
    }
}

__global__ __launch_bounds__(NTH) void srp_kernel(
    const float* __restrict__ g_anchor,
    const float* __restrict__ g_lr,
    const float* __restrict__ g_pw,
    const float* __restrict__ g_bl,
    const float* __restrict__ g_mask,
    const float* __restrict__ g_sbud,
    const float* __restrict__ g_pbud,
    const float* __restrict__ g_psp,
    const float* __restrict__ g_ppa,
    const int*  __restrict__ g_front,
    float* __restrict__ g_out,
    int n_rows)
{
    constexpr float MIN_SPEECH = 1.0f;
    constexpr float MAX_EXPAND = 3.0f;
    constexpr float MIN_BW = 0.1f;
    constexpr float BIAS_W = 0.15f;
    constexpr float INV_TEMP = 1.0f / 0.12f;

    __shared__ float sc[T_DIM];                 // 32 KB: scores
    __shared__ unsigned hist[NWAVE][256];       // 16 KB: per-wave histograms
    __shared__ unsigned s_tot[256];             // reduced histogram
    __shared__ float wred[NWAVE][4];
    __shared__ float s_scal[6];
    __shared__ unsigned sh_hb, sh_k1;           // pass A result
    __shared__ unsigned sh_lb, sh_k2;           // pass B result

    const int b = blockIdx.x;
    const int tid = threadIdx.x;
    const int wave = tid >> 6;
    const int lane = tid & 63;
    const long long row = (long long)b * T_DIM;
    const int f = g_front[b];

    // zero this wave's own histogram (same-wave LDS ops complete in order,
    // and only this wave atomics into hist[wave][*] -> no barrier needed)
    #pragma unroll
    for (int d = 0; d < 4; ++d) hist[wave][lane + 64 * d] = 0u;

    float A[8], Pp[8], Cc[8], Mm[8], TC[8];
    float a_ps = 0.f, a_pp = 0.f, a_ts = 0.f, a_cs = 0.f;

    // ---------- Pass 1: single read of all inputs; sums + scores + pass-A hist ----------
    #pragma unroll
    for (int j = 0; j < 2; ++j) {
        const int t0 = j * 4096 + (tid << 2);
        const float4 an4 = *reinterpret_cast<const float4*>(g_anchor + row + t0);
        const float4 lr4 = *reinterpret_cast<const float4*>(g_lr + row + t0);
        const float4 pw4 = *reinterpret_cast<const float4*>(g_pw + row + t0);
        const float4 bl4 = *reinterpret_cast<const float4*>(g_bl + row + t0);
        const float4 mk4 = *reinterpret_cast<const float4*>(g_mask + row + t0);
        const float4 ps4 = *reinterpret_cast<const float4*>(g_psp + row + t0);
        const float4 pp4 = *reinterpret_cast<const float4*>(g_ppa + row + t0);
        float4 s4;
        #pragma unroll
        for (int c = 0; c < 4; ++c) {
            const int i = (j << 2) + c;
            const int t = t0 + c;
            const float m   = (&mk4.x)[c];
            const float pre = (t < f) ? 1.0f : 0.0f;
            const float tail = m * (1.0f - pre);
            const float ps = (&ps4.x)[c];
            const float pp = (&pp4.x)[c];
            a_ps += ps * m * pre;
            a_pp += pp * m * pre;
            a_ts += tail;
            const float an = fmaxf((&an4.x)[c], MIN_SPEECH);
            const float cand = fminf(fmaxf(an * __expf((&lr4.x)[c]), MIN_SPEECH),
                                     an * MAX_EXPAND) * m;
            a_cs += cand * tail;
            const float s = (fmaxf((&pw4.x)[c], 0.0f)
                             + BIAS_W * (MIN_BW + fmaxf((&bl4.x)[c], 0.0f))) * m;
            (&s4.x)[c] = s;
            const unsigned key = (unsigned)fminf(s * KSCALE, 65535.0f);
            atomicAdd(&hist[wave][key >> 8], 1u);
            A[i]  = ps * m * m * pre;
            Pp[i] = pp * m * m * pre;
            Cc[i] = cand * tail * m;
            Mm[i] = m;
        }
        *reinterpret_cast<float4*>(&sc[t0]) = s4;
    }

    // wave-level reduce of the 4 accumulators
    #pragma unroll
    for (int o = 32; o > 0; o >>= 1) {
        a_ps += __shfl_down(a_ps, o, 64);
        a_pp += __shfl_down(a_pp, o, 64);
        a_ts += __shfl_down(a_ts, o, 64);
        a_cs += __shfl_down(a_cs, o, 64);
    }
    if (lane == 0) {
        wred[wave][0] = a_ps; wred[wave][1] = a_pp;
        wred[wave][2] = a_ts; wred[wave][3] = a_cs;
    }
    __syncthreads();

    // reduce 16 wave histograms; tid==0 computes row scalars
    if (tid < 256) {
        unsigned s = 0;
        #pragma unroll
        for (int w = 0; w < NWAVE; ++w) s += hist[w][tid];
        s_tot[tid] = s;
    }
    if (tid == 0) {
        float ps = 0.f, pp = 0.f, ts = 0.f, cs = 0.f;
        for (int w = 0; w < NWAVE; ++w) {
            ps += wred[w][0]; pp += wred[w][1];
            ts += wred[w][2]; cs += wred[w][3];
        }
        const float sb = fmaxf(g_sbud[b], ps + ts * MIN_SPEECH);
        const float pb = fmaxf(g_pbud[b], pp);
        const float rem_s = sb - ps;
        const float cts = fmaxf(cs, 1e-6f);
        s_scal[0] = (ts > 0.0f && rem_s > 0.0f) ? (rem_s / cts) : 0.0f;  // scale_s
        s_scal[1] = fmaxf(pb - pp, 0.0f);                                // rem_p
        s_scal[2] = ts;
        s_scal[3] = fmaxf(ts, 1.0f);
    }
    __syncthreads();

    // pass A scan (wave 0) + everyone re-zeros their own histogram
    #pragma unroll
    for (int d = 0; d < 4; ++d) hist[wave][lane + 64 * d] = 0u;
    if (wave == 0) scan_top256(s_tot, KEEP_K, lane, &sh_hb, &sh_k1);
    __syncthreads();

    // ---------- Pass B: low-byte histogram within selected high-byte bucket ----------
    const unsigned hb = sh_hb;
    #pragma unroll
    for (int j = 0; j < 2; ++j) {
        const int t0 = j * 4096 + (tid << 2);
        const float4 s4 = *reinterpret_cast<const float4*>(&sc[t0]);
        #pragma unroll
        for (int c = 0; c < 4; ++c) {
            const unsigned key = (unsigned)fminf((&s4.x)[c] * KSCALE, 65535.0f);
            if ((key >> 8) == hb) atomicAdd(&hist[wave][key & 0xFFu], 1u);
        }
    }
    __syncthreads();
    if (tid < 256) {
        unsigned s = 0;
        #pragma unroll
        for (int w = 0; w < NWAVE; ++w) s += hist[w][tid];
        s_tot[tid] = s;
    }
    __syncthreads();
    if (wave == 0) scan_top256(s_tot, sh_k1, lane, &sh_lb, &sh_k2);
    __syncthreads();

    const float thr = (float)((sh_hb << 8) | sh_lb) * INV_KSCALE;

    // ---------- Pass 2: gated denominator ----------
    const float inv_ts6 = 1e-6f / s_scal[3];
    float a_d = 0.0f;
    #pragma unroll
    for (int j = 0; j < 2; ++j) {
        const int t0 = j * 4096 + (tid << 2);
        const float4 s4 = *reinterpret_cast<const float4*>(&sc[t0]);
        #pragma unroll
        for (int c = 0; c < 4; ++c) {
            const int i = (j << 2) + c;
            const int t = t0 + c;
            const float m = Mm[i];
            const float pre = (t < f) ? 1.0f : 0.0f;
            const float tail = m * (1.0f - pre);
            const float s = (&s4.x)[c];
            const float gate = 1.0f / (1.0f + __expf(-(s - thr) * INV_TEMP));
            const float tc = s * gate * m * tail + tail * inv_ts6;
            a_d += tc * tail;
            TC[i] = tc * tail * m;
        }
    }
    #pragma unroll
    for (int o = 32; o > 0; o >>= 1) a_d += __shfl_down(a_d, o, 64);
    if (lane == 0) wred[wave][0] = a_d;
    __syncthreads();
    if (tid == 0) {
        float d = 0.f;
        for (int w = 0; w < NWAVE; ++w) d += wred[w][0];
        const float denom = fmaxf(d, 1e-6f);
        const float ts = s_scal[2];
        const float rem_p = s_scal[1];
        s_scal[4] = (ts > 0.0f && rem_p > 0.0f) ? (rem_p / denom) : 0.0f;  // scale_p
    }
    __syncthreads();

    // ---------- Pass 3: write outputs (non-temporal; consumed only by host check) ----------
    const float scale_s = s_scal[0];
    const float scale_p = s_scal[4];
    const long long out_off = (long long)n_rows * T_DIM;
    #pragma unroll
    for (int j = 0; j < 2; ++j) {
        const int t0 = j * 4096 + (tid << 2);
        nt4 vs, vp;
        #pragma unroll
        for (int c = 0; c < 4; ++c) {
            const int i = (j << 2) + c;
            vs[c] = A[i]  + Cc[i] * scale_s;
            vp[c] = Pp[i] + TC[i] * scale_p;
        }
        __builtin_nontemporal_store(vs, reinterpret_cast<nt4*>(g_out + row + t0));
        __builtin_nontemporal_store(vp, reinterpret_cast<nt4*>(g_out + out_off + row + t0));
    }
}

extern "C" void kernel_launch(void* const* d_in, const int* in_sizes, int n_in,
                              void* d_out, int out_size, void* d_ws, size_t ws_size,
                              hipStream_t stream) {
    const float* anchor = (const float*)d_in[0];
    const float* lr     = (const float*)d_in[1];
    const float* pw     = (const float*)d_in[2];
    const float* bl     = (const float*)d_in[3];
    const float* mask   = (const float*)d_in[4];
    const float* sbud   = (const float*)d_in[5];
    const float* pbud   = (const float*)d_in[6];
    const float* psp    = (const float*)d_in[7];
    const float* ppa    = (const float*)d_in[8];
    const int*   front  = (const int*)d_in[9];
    float* out = (float*)d_out;
    const int B = in_sizes[5];   // speech_budget_win has B elements
    srp_kernel<<<B, NTH, 0, stream>>>(anchor, lr, pw, bl, mask, sbud, pbud,
                                      psp, ppa, front, out, B);
}

// Round 4
// 169.508 us; speedup vs baseline: 1.0744x; 1.0098x over previous
//
#include <hip/hip_runtime.h>

#define T_DIM 8192
#define NTH 512
#define NWAVE 8
#define GROUPS 4
#define KEEP_K 2867                 // max(1, round(8192 * 0.35))
#define KSCALE 32768.0f             // 16-bit fixed-point key scale (scores < 2.0)
#define INV_KSCALE (1.0f / 32768.0f)

typedef float nt4 __attribute__((ext_vector_type(4)));  // native vec for nontemporal store

// Scan 256-bin histogram from the top, find digit where cumulative count
// reaches k. Executed by wave 0 only.
__device__ __forceinline__ void scan_top256(const unsigned* bins, unsigned k, int lane,
                                            unsigned* sh_digit, unsigned* sh_k) {
    const int r0 = lane * 4;
    const unsigned c0 = bins[255 - r0];
    const unsigned c1 = bins[255 - (r0 + 1)];
    const unsigned c2 = bins[255 - (r0 + 2)];
    const unsigned c3 = bins[255 - (r0 + 3)];
    const unsigned s1 = c0 + c1, s2 = s1 + c2, s3 = s2 + c3;
    unsigned tot = s3;
    #pragma unroll
    for (int off = 1; off < 64; off <<= 1) {
        const unsigned n = __shfl_up(tot, off, 64);
        if (lane >= off) tot += n;
    }
    const unsigned excl = tot - s3;
    const unsigned Pc[4] = { excl + c0, excl + s1, excl + s2, excl + s3 };
    unsigned prev = excl;
    #pragma unroll
    for (int c = 0; c < 4; ++c) {
        if (Pc[c] >= k && prev < k) {
            *sh_digit = (unsigned)(255 - (r0 + c));
            *sh_k = k - prev;
        }
        prev = Pc[c];
    }
}

__global__ __launch_bounds__(NTH, 4) void srp_kernel(
    const float* __restrict__ g_anchor,
    const float* __restrict__ g_lr,
    const float* __restrict__ g_pw,
    const float* __restrict__ g_bl,
    const float* __restrict__ g_mask,
    const float* __restrict__ g_sbud,
    const float* __restrict__ g_pbud,
    const float* __restrict__ g_psp,
    const float* __restrict__ g_ppa,
    const int*  __restrict__ g_front,
    float* __restrict__ g_out,
    int n_rows)
{
    constexpr float MIN_SPEECH = 1.0f;
    constexpr float MAX_EXPAND = 3.0f;
    constexpr float MIN_BW = 0.1f;
    constexpr float BIAS_W = 0.15f;
    constexpr float INV_TEMP = 1.0f / 0.12f;

    __shared__ unsigned ku[T_DIM / 2];          // 16 KB: packed 16-bit keys
    __shared__ unsigned hist[NWAVE][256];       // 8 KB: per-wave histograms
    __shared__ unsigned s_tot[256];
    __shared__ float wred[NWAVE][4];
    __shared__ float s_scal[6];
    __shared__ unsigned sh_hb, sh_k1, sh_lb, sh_k2;

    const int b = blockIdx.x;
    const int tid = threadIdx.x;
    const int wave = tid >> 6;
    const int lane = tid & 63;
    const long long row = (long long)b * T_DIM;
    const int f = g_front[b];

    // zero this wave's own histogram (wave-private -> no barrier needed)
    #pragma unroll
    for (int d = 0; d < 4; ++d) hist[wave][lane + 64 * d] = 0u;

    // per-element state: prefix/tail terms are mutually exclusive per element,
    // so one array each suffices (selected by pre at store time).
    float SC1[16];   // pre? ps*m^2 : cand*tail*m   (speech)
    float P1[16];    // pre? pp*m^2 : (pass2) tc*tail*m  (pause)
    float Mm[16];
    float a_ps = 0.f, a_pp = 0.f, a_ts = 0.f, a_cs = 0.f;

    // ---------- Pass 1: single read of all inputs; sums + keys + pass-A hist ----------
    #pragma unroll
    for (int g = 0; g < GROUPS; ++g) {
        const int t0 = g * 2048 + (tid << 2);
        const float4 an4 = *reinterpret_cast<const float4*>(g_anchor + row + t0);
        const float4 lr4 = *reinterpret_cast<const float4*>(g_lr + row + t0);
        const float4 pw4 = *reinterpret_cast<const float4*>(g_pw + row + t0);
        const float4 bl4 = *reinterpret_cast<const float4*>(g_bl + row + t0);
        const float4 mk4 = *reinterpret_cast<const float4*>(g_mask + row + t0);
        const float4 ps4 = *reinterpret_cast<const float4*>(g_psp + row + t0);
        const float4 pp4 = *reinterpret_cast<const float4*>(g_ppa + row + t0);
        unsigned kk0 = 0u, kk1 = 0u;
        #pragma unroll
        for (int c = 0; c < 4; ++c) {
            const int i = (g << 2) + c;
            const int t = t0 + c;
            const float m   = (&mk4.x)[c];
            const float pre = (t < f) ? 1.0f : 0.0f;
            const float tail = m * (1.0f - pre);
            const float ps = (&ps4.x)[c];
            const float pp = (&pp4.x)[c];
            a_ps += ps * m * pre;
            a_pp += pp * m * pre;
            a_ts += tail;
            const float an = fmaxf((&an4.x)[c], MIN_SPEECH);
            const float cand = fminf(fmaxf(an * __expf((&lr4.x)[c]), MIN_SPEECH),
                                     an * MAX_EXPAND) * m;
            a_cs += cand * tail;
            const float s = (fmaxf((&pw4.x)[c], 0.0f)
                             + BIAS_W * (MIN_BW + fmaxf((&bl4.x)[c], 0.0f))) * m;
            const unsigned key = (unsigned)fminf(s * KSCALE, 65535.0f);
            atomicAdd(&hist[wave][key >> 8], 1u);
            if (c < 2) kk0 |= key << (16 * c);
            else       kk1 |= key << (16 * (c - 2));
            SC1[i] = ps * m * m * pre + cand * tail * m;
            P1[i]  = pp * m * m * pre;
            Mm[i]  = m;
        }
        uint2 w2; w2.x = kk0; w2.y = kk1;
        *reinterpret_cast<uint2*>(&ku[t0 >> 1]) = w2;
    }

    // wave-level reduce of the 4 accumulators
    #pragma unroll
    for (int o = 32; o > 0; o >>= 1) {
        a_ps += __shfl_down(a_ps, o, 64);
        a_pp += __shfl_down(a_pp, o, 64);
        a_ts += __shfl_down(a_ts, o, 64);
        a_cs += __shfl_down(a_cs, o, 64);
    }
    if (lane == 0) {
        wred[wave][0] = a_ps; wred[wave][1] = a_pp;
        wred[wave][2] = a_ts; wred[wave][3] = a_cs;
    }
    __syncthreads();                                                    // B1

    if (tid < 256) {
        unsigned s = 0;
        #pragma unroll
        for (int w = 0; w < NWAVE; ++w) s += hist[w][tid];
        s_tot[tid] = s;
    }
    if (tid == 0) {
        float ps = 0.f, pp = 0.f, ts = 0.f, cs = 0.f;
        for (int w = 0; w < NWAVE; ++w) {
            ps += wred[w][0]; pp += wred[w][1];
            ts += wred[w][2]; cs += wred[w][3];
        }
        const float sb = fmaxf(g_sbud[b], ps + ts * MIN_SPEECH);
        const float pb = fmaxf(g_pbud[b], pp);
        const float rem_s = sb - ps;
        const float cts = fmaxf(cs, 1e-6f);
        s_scal[0] = (ts > 0.0f && rem_s > 0.0f) ? (rem_s / cts) : 0.0f;  // scale_s
        s_scal[1] = fmaxf(pb - pp, 0.0f);                                // rem_p
        s_scal[2] = ts;
        s_scal[3] = fmaxf(ts, 1.0f);
    }
    __syncthreads();                                                    // B2

    // ---- early speech store: only needs scale_s; overlaps the selection ----
    {
        const float scale_s = s_scal[0];
        #pragma unroll
        for (int g = 0; g < GROUPS; ++g) {
            const int t0 = g * 2048 + (tid << 2);
            nt4 vs;
            #pragma unroll
            for (int c = 0; c < 4; ++c) {
                const int i = (g << 2) + c;
                const int t = t0 + c;
                vs[c] = (t < f) ? SC1[i] : SC1[i] * scale_s;
            }
            __builtin_nontemporal_store(vs, reinterpret_cast<nt4*>(g_out + row + t0));
        }
    }
    // re-zero own histogram; wave0 scans pass A
    #pragma unroll
    for (int d = 0; d < 4; ++d) hist[wave][lane + 64 * d] = 0u;
    if (wave == 0) scan_top256(s_tot, KEEP_K, lane, &sh_hb, &sh_k1);
    __syncthreads();                                                    // B3

    // ---------- Pass B: low-byte histogram within selected high-byte bucket ----------
    const unsigned hb = sh_hb;
    #pragma unroll
    for (int g = 0; g < GROUPS; ++g) {
        const int t0 = g * 2048 + (tid << 2);
        const uint2 w2 = *reinterpret_cast<const uint2*>(&ku[t0 >> 1]);
        const unsigned k0 = w2.x & 0xFFFFu, k1 = w2.x >> 16;
        const unsigned k2 = w2.y & 0xFFFFu, k3 = w2.y >> 16;
        if ((k0 >> 8) == hb) atomicAdd(&hist[wave][k0 & 0xFFu], 1u);
        if ((k1 >> 8) == hb) atomicAdd(&hist[wave][k1 & 0xFFu], 1u);
        if ((k2 >> 8) == hb) atomicAdd(&hist[wave][k2 & 0xFFu], 1u);
        if ((k3 >> 8) == hb) atomicAdd(&hist[wave][k3 & 0xFFu], 1u);
    }
    __syncthreads();                                                    // B4
    if (tid < 256) {
        unsigned s = 0;
        #pragma unroll
        for (int w = 0; w < NWAVE; ++w) s += hist[w][tid];
        s_tot[tid] = s;
    }
    __syncthreads();                                                    // B5
    if (wave == 0) scan_top256(s_tot, sh_k1, lane, &sh_lb, &sh_k2);
    __syncthreads();                                                    // B6

    const float thr = (float)((sh_hb << 8) | sh_lb) * INV_KSCALE;

    // ---------- Pass 2: gated denominator (scores reconstructed from keys) ----------
    const float inv_ts6 = 1e-6f / s_scal[3];
    float a_d = 0.0f;
    #pragma unroll
    for (int g = 0; g < GROUPS; ++g) {
        const int t0 = g * 2048 + (tid << 2);
        const uint2 w2 = *reinterpret_cast<const uint2*>(&ku[t0 >> 1]);
        const unsigned kk[4] = { w2.x & 0xFFFFu, w2.x >> 16, w2.y & 0xFFFFu, w2.y >> 16 };
        #pragma unroll
        for (int c = 0; c < 4; ++c) {
            const int i = (g << 2) + c;
            const int t = t0 + c;
            const float m = Mm[i];
            const float pre = (t < f) ? 1.0f : 0.0f;
            const float tail = m * (1.0f - pre);
            const float s = (float)kk[c] * INV_KSCALE;
            const float gate = 1.0f / (1.0f + __expf(-(s - thr) * INV_TEMP));
            const float tc = s * gate * m * tail + tail * inv_ts6;
            a_d += tc * tail;
            P1[i] += tc * tail * m;     // zero for prefix elements
        }
    }
    #pragma unroll
    for (int o = 32; o > 0; o >>= 1) a_d += __shfl_down(a_d, o, 64);
    if (lane == 0) wred[wave][0] = a_d;
    __syncthreads();                                                    // B7
    if (tid == 0) {
        float d = 0.f;
        for (int w = 0; w < NWAVE; ++w) d += wred[w][0];
        const float denom = fmaxf(d, 1e-6f);
        const float ts = s_scal[2];
        const float rem_p = s_scal[1];
        s_scal[4] = (ts > 0.0f && rem_p > 0.0f) ? (rem_p / denom) : 0.0f;  // scale_p
    }
    __syncthreads();                                                    // B8

    // ---------- pause store ----------
    const float scale_p = s_scal[4];
    const long long out_off = (long long)n_rows * T_DIM;
    #pragma unroll
    for (int g = 0; g < GROUPS; ++g) {
        const int t0 = g * 2048 + (tid << 2);
        nt4 vp;
        #pragma unroll
        for (int c = 0; c < 4; ++c) {
            const int i = (g << 2) + c;
            const int t = t0 + c;
            vp[c] = (t < f) ? P1[i] : P1[i] * scale_p;
        }
        __builtin_nontemporal_store(vp, reinterpret_cast<nt4*>(g_out + out_off + row + t0));
    }
}

extern "C" void kernel_launch(void* const* d_in, const int* in_sizes, int n_in,
                              void* d_out, int out_size, void* d_ws, size_t ws_size,
                              hipStream_t stream) {
    const float* anchor = (const float*)d_in[0];
    const float* lr     = (const float*)d_in[1];
    const float* pw     = (const float*)d_in[2];
    const float* bl     = (const float*)d_in[3];
    const float* mask   = (const float*)d_in[4];
    const float* sbud   = (const float*)d_in[5];
    const float* pbud   = (const float*)d_in[6];
    const float* psp    = (const float*)d_in[7];
    const float* ppa    = (const float*)d_in[8];
    const int*   front  = (const int*)d_in[9];
    float* out = (float*)d_out;
    const int B = in_sizes[5];   // speech_budget_win has B elements
    srp_kernel<<<B, NTH, 0, stream>>>(anchor, lr, pw, bl, mask, sbud, pbud,
                                      psp, ppa, front, out, B);
}